// Round 3
// baseline (740.696 us; speedup 1.0000x reference)
//
#include <hip/hip_runtime.h>
#include <hip/hip_bf16.h>

// Problem constants
#define B_    32
#define H_    64
#define W_    64
#define C_    256
#define NH_   8
#define N_    16
#define PIX_  (B_*H_*W_)     // 131072
#define OUTPIX_ (B_*32*32)   // 32768

typedef __hip_bfloat16 bf16;

// ---------------------------------------------------------------------------
// K1: s0[8][16] (softmax row 0 of logits) and qv[8]. One block, 256 threads.
// logits[h,0,j] = kq[0, 128 + h*16 + j] + kq[j, h*16]
// ---------------------------------------------------------------------------
__global__ __launch_bounds__(256) void k1_setup(
    const float* __restrict__ emb,    // 16 x 128
    const float* __restrict__ wkq_w,  // 128 x 256
    const float* __restrict__ wkq_b,  // 256
    const float* __restrict__ wgq_w,  // 128 x 8
    const float* __restrict__ wgq_b,  // 8
    float* __restrict__ s0, float* __restrict__ qv) {
  __shared__ float lq[128];     // q_part[0, c], c = h*16+j
  __shared__ float lk[16][8];   // k_part[j, h*16]
  int t = threadIdx.x;
  if (t < 128) {
    float acc = wkq_b[128 + t];
    for (int e = 0; e < 128; ++e)
      acc += emb[e] * wkq_w[e * 256 + 128 + t];
    lq[t] = acc;
  } else {
    int idx = t - 128; int j = idx >> 3, h = idx & 7;
    float acc = wkq_b[h * 16];
    for (int e = 0; e < 128; ++e)
      acc += emb[j * 128 + e] * wkq_w[e * 256 + h * 16];
    lk[j][h] = acc;
  }
  __syncthreads();
  if (t < 8) {
    float l[16]; float m = -1e30f;
    for (int j = 0; j < 16; ++j) { l[j] = lq[t * 16 + j] + lk[j][t]; m = fmaxf(m, l[j]); }
    float s = 0.f;
    for (int j = 0; j < 16; ++j) { l[j] = expf(l[j] - m); s += l[j]; }
    float inv = 1.f / s;
    for (int j = 0; j < 16; ++j) s0[t * 16 + j] = l[j] * inv;
    // qv = actq[N-2] = row 14 of (neuron_emb @ wgactq + b)
    float acc = wgq_b[t];
    for (int e = 0; e < 128; ++e) acc += emb[14 * 128 + e] * wgq_w[e * 8 + t];
    qv[t] = acc;
  }
}

// ---------------------------------------------------------------------------
// K2: g = relu(qv + inps@wgactk + b) (store fp32), denom[b][a] += g.
// One wave handles 8 pixels; block = 4 waves = 32 pixels.
// ---------------------------------------------------------------------------
__global__ __launch_bounds__(256) void k2_gate(
    const float* __restrict__ inps,   // (B,H,W,256) fp32
    const float* __restrict__ wgk_w,  // 256 x 8
    const float* __restrict__ wgk_b,  // 8
    const float* __restrict__ qv,
    float* __restrict__ gbuf,         // (PIX, 8) fp32
    float* __restrict__ denom) {      // (B, 8) fp32, pre-zeroed
  __shared__ float sden[8];
  int t = threadIdx.x;
  if (t < 8) sden[t] = 0.f;
  __syncthreads();
  int wave = t >> 6, lane = t & 63;
  long pix0 = (long)blockIdx.x * 32 + wave * 8;
  // per-lane slice of wgactk: rows lane*4 .. lane*4+3
  float wk[4][8];
#pragma unroll
  for (int r = 0; r < 4; ++r)
#pragma unroll
    for (int a = 0; a < 8; ++a)
      wk[r][a] = wgk_w[(lane * 4 + r) * 8 + a];
  float qvb[8];
#pragma unroll
  for (int a = 0; a < 8; ++a) qvb[a] = qv[a] + wgk_b[a];
  float dloc[8];
#pragma unroll
  for (int a = 0; a < 8; ++a) dloc[a] = 0.f;

  for (int it = 0; it < 8; ++it) {
    long p = pix0 + it;
    float4 x = *(const float4*)(inps + p * 256 + (lane << 2));
    float part[8];
#pragma unroll
    for (int a = 0; a < 8; ++a)
      part[a] = x.x * wk[0][a] + x.y * wk[1][a] + x.z * wk[2][a] + x.w * wk[3][a];
#pragma unroll
    for (int off = 32; off > 0; off >>= 1) {
#pragma unroll
      for (int a = 0; a < 8; ++a)
        part[a] += __shfl_down(part[a], (unsigned)off, 64);
    }
    if (lane == 0) {
      float gg[8];
#pragma unroll
      for (int a = 0; a < 8; ++a) {
        gg[a] = fmaxf(qvb[a] + part[a], 0.f);
        dloc[a] += gg[a];
      }
      *(float4*)(gbuf + p * 8)     = make_float4(gg[0], gg[1], gg[2], gg[3]);
      *(float4*)(gbuf + p * 8 + 4) = make_float4(gg[4], gg[5], gg[6], gg[7]);
    }
  }
  if (lane == 0) {
#pragma unroll
    for (int a = 0; a < 8; ++a) atomicAdd(&sden[a], dloc[a]);
  }
  __syncthreads();
  if (t < 8) {
    int b = (int)(((long)blockIdx.x * 32) >> 12);   // 4096 pixels per image
    atomicAdd(&denom[b * 8 + t], sden[t]);
  }
}

// ---------------------------------------------------------------------------
// K3a: vs[p,ch] = (inps[p,:] @ wv[:,ch] + wv_b[ch]) * (4096/(denom+1e-6))*g[p,h]
// Block: 16 pixels x 256 ch. Thread t = ch. fp32 VALU GEMM. vs stored bf16.
// ---------------------------------------------------------------------------
__global__ __launch_bounds__(256) void k3a_vscaled(
    const float* __restrict__ inps, const float* __restrict__ wv_w,
    const float* __restrict__ wv_b, const float* __restrict__ gbuf,
    const float* __restrict__ denom, bf16* __restrict__ vs) {
  __shared__ __align__(16) float Ash[16][260];  // 16 px x 256, pad
  __shared__ float scf[16][8];
  int t = threadIdx.x;
  long pix0 = (long)blockIdx.x * 16;
#pragma unroll
  for (int it = 0; it < 4; ++it) {
    int idx = it * 1024 + t * 4;          // 4096 elems total
    int px = idx >> 8, col = idx & 255;
    float4 v = *(const float4*)(inps + pix0 * 256 + idx);
    *(float4*)&Ash[px][col] = v;
  }
  if (t < 128) {
    int p = t >> 3, a = t & 7;
    int b = (int)(pix0 >> 12);
    scf[p][a] = 4096.0f / (denom[b * 8 + a] + 1e-6f) * gbuf[(pix0 + p) * 8 + a];
  }
  __syncthreads();
  float acc[16];
#pragma unroll
  for (int p = 0; p < 16; ++p) acc[p] = 0.f;
  for (int k0 = 0; k0 < 256; k0 += 4) {
    float w0 = wv_w[(k0 + 0) * 256 + t];
    float w1 = wv_w[(k0 + 1) * 256 + t];
    float w2 = wv_w[(k0 + 2) * 256 + t];
    float w3 = wv_w[(k0 + 3) * 256 + t];
#pragma unroll
    for (int p = 0; p < 16; ++p) {
      float4 a4 = *(const float4*)&Ash[p][k0];
      acc[p] += a4.x * w0 + a4.y * w1 + a4.z * w2 + a4.w * w3;
    }
  }
  float wb = wv_b[t];
  int hh = t >> 5;
#pragma unroll
  for (int p = 0; p < 16; ++p) {
    float v = (acc[p] + wb) * scf[p][hh];
    vs[(pix0 + p) * 256 + t] = __float2bfloat16(v);
  }
}

// ---------------------------------------------------------------------------
// K3b: patch gather (pad=1, stride=2, 4x4 taps) weighted by s0, then @ wf + b.
// Block = one (b,x) row of 32 output pixels. Thread t = channel / out-feature.
// Output is fp32 (reference returns float32).
// ---------------------------------------------------------------------------
__global__ __launch_bounds__(256) void k3b_out(
    const bf16* __restrict__ vs, const float* __restrict__ s0,
    const float* __restrict__ wf_w, const float* __restrict__ wf_b,
    float* __restrict__ out) {
  __shared__ __align__(16) float opsh[32][260];   // 32 out-px x 256
  int t = threadIdx.x;
  int bx = blockIdx.x;              // b*32 + x
  int b = bx >> 5, x = bx & 31;
  int h = t >> 5;
  float s0r[16];
#pragma unroll
  for (int n = 0; n < 16; ++n) s0r[n] = s0[h * 16 + n];
  const bf16* vsb = vs + (long)b * (64 * 64 * 256);

  // phase 1: op[y][ch] = sum_n s0[h,n] * vs[b, 2x+i-1, 2y+j-1, ch]
  for (int y = 0; y < 32; ++y) {
    float accp = 0.f;
#pragma unroll
    for (int i = 0; i < 4; ++i) {
      int r = 2 * x + i - 1;
      if (r < 0 || r >= 64) continue;       // block-uniform
#pragma unroll
      for (int j = 0; j < 4; ++j) {
        int c = 2 * y + j - 1;
        if (c < 0 || c >= 64) continue;     // block-uniform
        accp += s0r[i * 4 + j] * (float)vsb[((long)r * 64 + c) * 256 + t];
      }
    }
    opsh[y][t] = accp;
  }
  __syncthreads();

  // phase 2: out[y][f] = op[y][:] @ wf[:,f] + wf_b[f]
  float acc[32];
#pragma unroll
  for (int p = 0; p < 32; ++p) acc[p] = 0.f;
  for (int k0 = 0; k0 < 256; k0 += 4) {
    float w0 = wf_w[(k0 + 0) * 256 + t];
    float w1 = wf_w[(k0 + 1) * 256 + t];
    float w2 = wf_w[(k0 + 2) * 256 + t];
    float w3 = wf_w[(k0 + 3) * 256 + t];
#pragma unroll
    for (int p = 0; p < 32; ++p) {
      float4 o = *(const float4*)&opsh[p][k0];
      acc[p] += o.x * w0 + o.y * w1 + o.z * w2 + o.w * w3;
    }
  }
  float wb = wf_b[t];
  long out0 = (long)bx * 32 * 256;
#pragma unroll
  for (int p = 0; p < 32; ++p)
    out[out0 + p * 256 + t] = acc[p] + wb;
}

// ---------------------------------------------------------------------------
// Workspace layout (floats from base):
//   s0: 0..128 | qv: 128..136 | denom: 256..512 (zeroed)
//   gbuf: 1024..1049600 | vs(bf16): byte 4198400.. (+67 MB). Total ~71.3 MB.
// ---------------------------------------------------------------------------
extern "C" void kernel_launch(void* const* d_in, const int* in_sizes, int n_in,
                              void* d_out, int out_size, void* d_ws, size_t ws_size,
                              hipStream_t stream) {
  const float* inps  = (const float*)d_in[0];
  const float* emb   = (const float*)d_in[1];
  const float* wkq_w = (const float*)d_in[2];
  const float* wkq_b = (const float*)d_in[3];
  const float* wv_w  = (const float*)d_in[4];
  const float* wv_b  = (const float*)d_in[5];
  const float* wgq_w = (const float*)d_in[6];
  const float* wgq_b = (const float*)d_in[7];
  const float* wgk_w = (const float*)d_in[8];
  const float* wgk_b = (const float*)d_in[9];
  const float* wf_w  = (const float*)d_in[10];
  const float* wf_b  = (const float*)d_in[11];

  float* wsf   = (float*)d_ws;
  float* s0f   = wsf;
  float* qvf   = wsf + 128;
  float* denom = wsf + 256;
  float* gbuf  = wsf + 1024;
  bf16*  vsb   = (bf16*)(wsf + 1024 + 1048576);
  float* outp  = (float*)d_out;

  hipMemsetAsync((void*)denom, 0, 1024, stream);
  k1_setup<<<1, 256, 0, stream>>>(emb, wkq_w, wkq_b, wgq_w, wgq_b, s0f, qvf);
  k2_gate<<<PIX_ / 32, 256, 0, stream>>>(inps, wgk_w, wgk_b, qvf, gbuf, denom);
  k3a_vscaled<<<PIX_ / 16, 256, 0, stream>>>(inps, wv_w, wv_b, gbuf, denom, vsb);
  k3b_out<<<OUTPIX_ / 32, 256, 0, stream>>>(vsb, s0f, wf_w, wf_b, outp);
}

// Round 4
// 446.085 us; speedup vs baseline: 1.6604x; 1.6604x over previous
//
#include <hip/hip_runtime.h>
#include <hip/hip_bf16.h>

// Problem constants
#define B_    32
#define H_    64
#define W_    64
#define C_    256
#define NH_   8
#define N_    16
#define PIX_  (B_*H_*W_)     // 131072
#define OUTPIX_ (B_*32*32)   // 32768

typedef __hip_bfloat16 bf16;
typedef __attribute__((ext_vector_type(8))) short bf16x8;   // 8 bf16 = 4 VGPR
typedef __attribute__((ext_vector_type(4))) float f32x4;

union FragU { bf16x8 v; unsigned u[4]; unsigned short s[8]; };

__device__ __forceinline__ unsigned pk2(float a, float b) {
  union { __hip_bfloat162 h2; unsigned u; } c;
  c.h2 = __float22bfloat162_rn(make_float2(a, b));
  return c.u;
}

// ---------------------------------------------------------------------------
// K1: s0[8][16] (softmax row 0 of logits) and qv[8]. One block.
// ---------------------------------------------------------------------------
__global__ __launch_bounds__(256) void k1_setup(
    const float* __restrict__ emb, const float* __restrict__ wkq_w,
    const float* __restrict__ wkq_b, const float* __restrict__ wgq_w,
    const float* __restrict__ wgq_b,
    float* __restrict__ s0, float* __restrict__ qv) {
  __shared__ float lq[128];
  __shared__ float lk[16][8];
  int t = threadIdx.x;
  if (t < 128) {
    float acc = wkq_b[128 + t];
    for (int e = 0; e < 128; ++e) acc += emb[e] * wkq_w[e * 256 + 128 + t];
    lq[t] = acc;
  } else {
    int idx = t - 128; int j = idx >> 3, h = idx & 7;
    float acc = wkq_b[h * 16];
    for (int e = 0; e < 128; ++e) acc += emb[j * 128 + e] * wkq_w[e * 256 + h * 16];
    lk[j][h] = acc;
  }
  __syncthreads();
  if (t < 8) {
    float l[16]; float m = -1e30f;
    for (int j = 0; j < 16; ++j) { l[j] = lq[t * 16 + j] + lk[j][t]; m = fmaxf(m, l[j]); }
    float s = 0.f;
    for (int j = 0; j < 16; ++j) { l[j] = expf(l[j] - m); s += l[j]; }
    float inv = 1.f / s;
    for (int j = 0; j < 16; ++j) s0[t * 16 + j] = l[j] * inv;
    float acc = wgq_b[t];
    for (int e = 0; e < 128; ++e) acc += emb[14 * 128 + e] * wgq_w[e * 8 + t];
    qv[t] = acc;
  }
}

// ---------------------------------------------------------------------------
// Prep: wvT_bf16[n][k] = wv[k][n];  wfT_bf16[n][k] = wf[k][n].  (256x256 each)
// ---------------------------------------------------------------------------
__global__ __launch_bounds__(256) void prep_t(
    const float* __restrict__ wv, const float* __restrict__ wf,
    bf16* __restrict__ wvT, bf16* __restrict__ wfT) {
  int k = blockIdx.x, n = threadIdx.x;
  wvT[n * 256 + k] = __float2bfloat16(wv[k * 256 + n]);
  wfT[n * 256 + k] = __float2bfloat16(wf[k * 256 + n]);
}

// ---------------------------------------------------------------------------
// K2: g = relu(qv + inps@wgactk + b) (fp32), denom[b][a] += g.  (unchanged)
// ---------------------------------------------------------------------------
__global__ __launch_bounds__(256) void k2_gate(
    const float* __restrict__ inps, const float* __restrict__ wgk_w,
    const float* __restrict__ wgk_b, const float* __restrict__ qv,
    float* __restrict__ gbuf, float* __restrict__ denom) {
  __shared__ float sden[8];
  int t = threadIdx.x;
  if (t < 8) sden[t] = 0.f;
  __syncthreads();
  int wave = t >> 6, lane = t & 63;
  long pix0 = (long)blockIdx.x * 32 + wave * 8;
  float wk[4][8];
#pragma unroll
  for (int r = 0; r < 4; ++r)
#pragma unroll
    for (int a = 0; a < 8; ++a) wk[r][a] = wgk_w[(lane * 4 + r) * 8 + a];
  float qvb[8];
#pragma unroll
  for (int a = 0; a < 8; ++a) qvb[a] = qv[a] + wgk_b[a];
  float dloc[8];
#pragma unroll
  for (int a = 0; a < 8; ++a) dloc[a] = 0.f;
  for (int it = 0; it < 8; ++it) {
    long p = pix0 + it;
    float4 x = *(const float4*)(inps + p * 256 + (lane << 2));
    float part[8];
#pragma unroll
    for (int a = 0; a < 8; ++a)
      part[a] = x.x * wk[0][a] + x.y * wk[1][a] + x.z * wk[2][a] + x.w * wk[3][a];
#pragma unroll
    for (int off = 32; off > 0; off >>= 1) {
#pragma unroll
      for (int a = 0; a < 8; ++a) part[a] += __shfl_down(part[a], (unsigned)off, 64);
    }
    if (lane == 0) {
      float gg[8];
#pragma unroll
      for (int a = 0; a < 8; ++a) { gg[a] = fmaxf(qvb[a] + part[a], 0.f); dloc[a] += gg[a]; }
      *(float4*)(gbuf + p * 8)     = make_float4(gg[0], gg[1], gg[2], gg[3]);
      *(float4*)(gbuf + p * 8 + 4) = make_float4(gg[4], gg[5], gg[6], gg[7]);
    }
  }
  if (lane == 0) {
#pragma unroll
    for (int a = 0; a < 8; ++a) atomicAdd(&sden[a], dloc[a]);
  }
  __syncthreads();
  if (t < 8) {
    int b = (int)(((long)blockIdx.x * 32) >> 12);
    atomicAdd(&denom[b * 8 + t], sden[t]);
  }
}

// ---------------------------------------------------------------------------
// K3a (MFMA): vs = (inps @ wv + b) * act.  Block: 64 pixels x 256 cols.
// Waves 2x2: wave tile M=32 x N=128 -> 2 Mfrag x 8 Nfrag (64 acc VGPR).
// A-frags: fp32 from global, cvt->bf16 in-register. B-frags: wvT (L2).
// No LDS in K-loop; no barriers.
// ---------------------------------------------------------------------------
__global__ __launch_bounds__(256) void k3a_mfma(
    const float* __restrict__ inps, const bf16* __restrict__ wvT,
    const float* __restrict__ wv_b, const float* __restrict__ gbuf,
    const float* __restrict__ denom, bf16* __restrict__ vs) {
  __shared__ float scf[64][8];
  int t = threadIdx.x;
  long pix0 = (long)blockIdx.x * 64;
  {
    int b = (int)(pix0 >> 12);
    for (int i = t; i < 512; i += 256) {
      int p = i >> 3, a = i & 7;
      scf[p][a] = 4096.0f / (denom[b * 8 + a] + 1e-6f) * gbuf[(pix0 + p) * 8 + a];
    }
  }
  __syncthreads();
  int wave = t >> 6, lane = t & 63;
  int mw = wave >> 1, nw = wave & 1;
  int m0 = mw * 32;            // local row base
  int n0 = nw * 128;           // col base
  int lm = lane & 15, q = lane >> 4;

  f32x4 acc[2][8];
#pragma unroll
  for (int mf = 0; mf < 2; ++mf)
#pragma unroll
    for (int nf = 0; nf < 8; ++nf) acc[mf][nf] = (f32x4){0.f, 0.f, 0.f, 0.f};

  const float* arow0 = inps + (pix0 + m0 + lm) * 256;
  const float* arow1 = arow0 + 16 * 256;
  const bf16*  brow  = wvT + (n0 + lm) * 256;

  for (int ks = 0; ks < 8; ++ks) {
    int kof = ks * 32 + q * 8;
    FragU a0, a1;
    {
      float4 xa = *(const float4*)(arow0 + kof);
      float4 xb = *(const float4*)(arow0 + kof + 4);
      a0.u[0] = pk2(xa.x, xa.y); a0.u[1] = pk2(xa.z, xa.w);
      a0.u[2] = pk2(xb.x, xb.y); a0.u[3] = pk2(xb.z, xb.w);
      float4 ya = *(const float4*)(arow1 + kof);
      float4 yb = *(const float4*)(arow1 + kof + 4);
      a1.u[0] = pk2(ya.x, ya.y); a1.u[1] = pk2(ya.z, ya.w);
      a1.u[2] = pk2(yb.x, yb.y); a1.u[3] = pk2(yb.z, yb.w);
    }
    FragU bfr[8];
#pragma unroll
    for (int nf = 0; nf < 8; ++nf)
      bfr[nf].v = *(const bf16x8*)(brow + nf * 16 * 256 + kof);
#pragma unroll
    for (int nf = 0; nf < 8; ++nf) {
      acc[0][nf] = __builtin_amdgcn_mfma_f32_16x16x32_bf16(a0.v, bfr[nf].v, acc[0][nf], 0, 0, 0);
      acc[1][nf] = __builtin_amdgcn_mfma_f32_16x16x32_bf16(a1.v, bfr[nf].v, acc[1][nf], 0, 0, 0);
    }
  }

  // Epilogue: vs = (acc + wv_b) * scf[row][head]
#pragma unroll
  for (int nf = 0; nf < 8; ++nf) {
    int col = n0 + nf * 16 + lm;
    float wb = wv_b[col];
    int h = col >> 5;
#pragma unroll
    for (int mf = 0; mf < 2; ++mf) {
#pragma unroll
      for (int r = 0; r < 4; ++r) {
        int rl = m0 + mf * 16 + q * 4 + r;
        float v = (acc[mf][nf][r] + wb) * scf[rl][h];
        vs[(pix0 + rl) * 256 + col] = __float2bfloat16(v);
      }
    }
  }
}

// ---------------------------------------------------------------------------
// K3b (MFMA): patch gather weighted by s0 (fp32 VALU, store op as bf16 LDS),
// then op @ wf + b via MFMA against L2-resident wfT. Block = (b,x) row.
// ---------------------------------------------------------------------------
__global__ __launch_bounds__(256) void k3b_mfma(
    const bf16* __restrict__ vs, const float* __restrict__ s0,
    const bf16* __restrict__ wfT, const float* __restrict__ wf_b,
    float* __restrict__ out) {
  __shared__ __align__(16) unsigned short opsh[32][264];   // bf16 bits, pad 8
  int t = threadIdx.x;
  int bx = blockIdx.x;
  int b = bx >> 5, x = bx & 31;
  int h = t >> 5;
  float s0r[16];
#pragma unroll
  for (int n = 0; n < 16; ++n) s0r[n] = s0[h * 16 + n];
  const bf16* vsb = vs + (long)b * (64 * 64 * 256);

  // phase 1: op[y][ch] = sum_n s0[h,n] * vs[b, 2x+i-1, 2y+j-1, ch]
  for (int y = 0; y < 32; ++y) {
    float accp = 0.f;
#pragma unroll
    for (int i = 0; i < 4; ++i) {
      int r = 2 * x + i - 1;
      if (r < 0 || r >= 64) continue;
#pragma unroll
      for (int j = 0; j < 4; ++j) {
        int c = 2 * y + j - 1;
        if (c < 0 || c >= 64) continue;
        accp += s0r[i * 4 + j] * __bfloat162float(vsb[((long)r * 64 + c) * 256 + t]);
      }
    }
    bf16 hb = __float2bfloat16(accp);
    opsh[y][t] = *(unsigned short*)&hb;
  }
  __syncthreads();

  // phase 2: MFMA  out[32 x 256] = op[32 x 256k] @ wf[256k x 256]
  int wave = t >> 6, lane = t & 63;
  int n0 = wave * 64;
  int lm = lane & 15, q = lane >> 4;
  f32x4 acc[2][4];
#pragma unroll
  for (int mf = 0; mf < 2; ++mf)
#pragma unroll
    for (int nf = 0; nf < 4; ++nf) acc[mf][nf] = (f32x4){0.f, 0.f, 0.f, 0.f};
  const bf16* brow = wfT + (n0 + lm) * 256;
  for (int ks = 0; ks < 8; ++ks) {
    int kof = ks * 32 + q * 8;
    FragU a0, a1;
    a0.v = *(const bf16x8*)(&opsh[lm][kof]);
    a1.v = *(const bf16x8*)(&opsh[16 + lm][kof]);
    FragU bfr[4];
#pragma unroll
    for (int nf = 0; nf < 4; ++nf)
      bfr[nf].v = *(const bf16x8*)(brow + nf * 16 * 256 + kof);
#pragma unroll
    for (int nf = 0; nf < 4; ++nf) {
      acc[0][nf] = __builtin_amdgcn_mfma_f32_16x16x32_bf16(a0.v, bfr[nf].v, acc[0][nf], 0, 0, 0);
      acc[1][nf] = __builtin_amdgcn_mfma_f32_16x16x32_bf16(a1.v, bfr[nf].v, acc[1][nf], 0, 0, 0);
    }
  }
  long out0 = (long)bx * 32 * 256;
#pragma unroll
  for (int nf = 0; nf < 4; ++nf) {
    int col = n0 + nf * 16 + lm;
    float wb = wf_b[col];
#pragma unroll
    for (int mf = 0; mf < 2; ++mf) {
#pragma unroll
      for (int r = 0; r < 4; ++r) {
        int row = mf * 16 + q * 4 + r;
        out[out0 + row * 256 + col] = acc[mf][nf][r] + wb;
      }
    }
  }
}

// ---------------------------------------------------------------------------
// Workspace (floats from base): s0 0..128 | qv 128..136 | denom 256..512
// gbuf 1024..1049600 | wvT(bf16) @f1049600 (+32768f) | wfT @f1082368 (+32768f)
// vs(bf16) @f1115136 (+64MB).  Total ~71.6 MB.
// ---------------------------------------------------------------------------
extern "C" void kernel_launch(void* const* d_in, const int* in_sizes, int n_in,
                              void* d_out, int out_size, void* d_ws, size_t ws_size,
                              hipStream_t stream) {
  const float* inps  = (const float*)d_in[0];
  const float* emb   = (const float*)d_in[1];
  const float* wkq_w = (const float*)d_in[2];
  const float* wkq_b = (const float*)d_in[3];
  const float* wv_w  = (const float*)d_in[4];
  const float* wv_b  = (const float*)d_in[5];
  const float* wgq_w = (const float*)d_in[6];
  const float* wgq_b = (const float*)d_in[7];
  const float* wgk_w = (const float*)d_in[8];
  const float* wgk_b = (const float*)d_in[9];
  const float* wf_w  = (const float*)d_in[10];
  const float* wf_b  = (const float*)d_in[11];

  float* wsf   = (float*)d_ws;
  float* s0f   = wsf;
  float* qvf   = wsf + 128;
  float* denom = wsf + 256;
  float* gbuf  = wsf + 1024;
  bf16*  wvT   = (bf16*)(wsf + 1049600);
  bf16*  wfT   = (bf16*)(wsf + 1049600 + 32768);
  bf16*  vsb   = (bf16*)(wsf + 1049600 + 65536);
  float* outp  = (float*)d_out;

  hipMemsetAsync((void*)denom, 0, 1024, stream);
  k1_setup<<<1, 256, 0, stream>>>(emb, wkq_w, wkq_b, wgq_w, wgq_b, s0f, qvf);
  prep_t<<<256, 256, 0, stream>>>(wv_w, wf_w, wvT, wfT);
  k2_gate<<<PIX_ / 32, 256, 0, stream>>>(inps, wgk_w, wgk_b, qvf, gbuf, denom);
  k3a_mfma<<<PIX_ / 64, 256, 0, stream>>>(inps, wvT, wv_b, gbuf, denom, vsb);
  k3b_mfma<<<OUTPIX_ / 32, 256, 0, stream>>>(vsb, s0f, wfT, wf_b, outp);
}

// Round 5
// 382.653 us; speedup vs baseline: 1.9357x; 1.1658x over previous
//
#include <hip/hip_runtime.h>
#include <hip/hip_bf16.h>

// Problem constants
#define B_    32
#define H_    64
#define W_    64
#define C_    256
#define NH_   8
#define N_    16
#define PIX_  (B_*H_*W_)     // 131072
#define OUTPIX_ (B_*32*32)   // 32768

typedef __hip_bfloat16 bf16;
typedef __attribute__((ext_vector_type(8))) short bf16x8;   // 8 bf16 = 4 VGPR
typedef __attribute__((ext_vector_type(4))) float f32x4;

__device__ __forceinline__ float bf2f(unsigned short u) {
  union { unsigned int i; float f; } v; v.i = ((unsigned int)u) << 16; return v.f;
}
__device__ __forceinline__ unsigned pk2(float a, float b) {
  union { __hip_bfloat162 h2; unsigned u; } c;
  c.h2 = __float22bfloat162_rn(make_float2(a, b));
  return c.u;
}

// ---------------------------------------------------------------------------
// K1: s0[8][16] (softmax row 0 of logits) and qv[8]. One block.
// ---------------------------------------------------------------------------
__global__ __launch_bounds__(256) void k1_setup(
    const float* __restrict__ emb, const float* __restrict__ wkq_w,
    const float* __restrict__ wkq_b, const float* __restrict__ wgq_w,
    const float* __restrict__ wgq_b,
    float* __restrict__ s0, float* __restrict__ qv) {
  __shared__ float lq[128];
  __shared__ float lk[16][8];
  int t = threadIdx.x;
  if (t < 128) {
    float acc = wkq_b[128 + t];
    for (int e = 0; e < 128; ++e) acc += emb[e] * wkq_w[e * 256 + 128 + t];
    lq[t] = acc;
  } else {
    int idx = t - 128; int j = idx >> 3, h = idx & 7;
    float acc = wkq_b[h * 16];
    for (int e = 0; e < 128; ++e) acc += emb[j * 128 + e] * wkq_w[e * 256 + h * 16];
    lk[j][h] = acc;
  }
  __syncthreads();
  if (t < 8) {
    float l[16]; float m = -1e30f;
    for (int j = 0; j < 16; ++j) { l[j] = lq[t * 16 + j] + lk[j][t]; m = fmaxf(m, l[j]); }
    float s = 0.f;
    for (int j = 0; j < 16; ++j) { l[j] = expf(l[j] - m); s += l[j]; }
    float inv = 1.f / s;
    for (int j = 0; j < 16; ++j) s0[t * 16 + j] = l[j] * inv;
    float acc = wgq_b[t];
    for (int e = 0; e < 128; ++e) acc += emb[14 * 128 + e] * wgq_w[e * 8 + t];
    qv[t] = acc;
  }
}

// ---------------------------------------------------------------------------
// prep: LDS-tiled transposes to bf16.
//   blocks 0..15 : wvT[n][k]  = wv[k][n]   (64x64 tiles)
//   blocks 16..31: wfT[n][k]  = wf[k][n]
//   block  32    : wgkT[a][k] = wgk[k][a]  (rows 8..15 zero)
// ---------------------------------------------------------------------------
__global__ __launch_bounds__(256) void prep(
    const float* __restrict__ wv, const float* __restrict__ wf,
    const float* __restrict__ wgk,
    bf16* __restrict__ wvT, bf16* __restrict__ wfT, bf16* __restrict__ wgkT) {
  int bid = blockIdx.x, t = threadIdx.x;
  if (bid < 32) {
    __shared__ unsigned short tile[64][72];
    const float* src = (bid < 16) ? wv : wf;
    bf16* dst = (bid < 16) ? wvT : wfT;
    int tb = bid & 15, tr = tb >> 2, tc = tb & 3;
#pragma unroll
    for (int it = 0; it < 16; ++it) {
      int idx = it * 256 + t, row = idx >> 6, col = idx & 63;
      bf16 h = __float2bfloat16(src[(tr * 64 + row) * 256 + tc * 64 + col]);
      tile[row][col] = *(unsigned short*)&h;
    }
    __syncthreads();
#pragma unroll
    for (int it = 0; it < 16; ++it) {
      int idx = it * 256 + t, row = idx >> 6, col = idx & 63;
      dst[(tc * 64 + row) * 256 + (tr * 64 + col)] = *(bf16*)&tile[col][row];
    }
  } else {
    __shared__ float g[2048];
#pragma unroll
    for (int it = 0; it < 8; ++it) g[it * 256 + t] = wgk[it * 256 + t];
    __syncthreads();
#pragma unroll
    for (int it = 0; it < 16; ++it) {
      int idx = it * 256 + t, a = idx >> 8, k = idx & 255;
      float v = (a < 8) ? g[k * 8 + a] : 0.f;
      wgkT[a * 256 + k] = __float2bfloat16(v);
    }
  }
}

// ---------------------------------------------------------------------------
// kA (fused gate + v-GEMM): per 64-px block:
//   vraw = inps @ wv + wv_b          (bf16 out, no scale yet)
//   g    = relu(qv + inps @ wgk + b) -> gbuf; denom += sum(g)
// inps staged once: fp32 coalesced -> bf16 LDS (pad 264). 512 thr = 8 waves,
// wave tile M32xN64. Gate rides waves nw==0 with one extra B-frag (wgkT).
// ---------------------------------------------------------------------------
__global__ __launch_bounds__(512) void kA(
    const float* __restrict__ inps, const bf16* __restrict__ wvT,
    const bf16* __restrict__ wgkT, const float* __restrict__ wv_b,
    const float* __restrict__ wgk_b, const float* __restrict__ qv,
    bf16* __restrict__ vraw, float* __restrict__ gbuf,
    float* __restrict__ denom) {
  __shared__ __align__(16) unsigned short ldsA[64][264];
  __shared__ float sden[8];
  __shared__ float qvb_s[8];
  int t = threadIdx.x;
  long pix0 = (long)blockIdx.x * 64;
  if (t < 8) { sden[t] = 0.f; qvb_s[t] = qv[t] + wgk_b[t]; }
  // stage 64x256 fp32 -> bf16 LDS (coalesced 1KB/wave loads)
  const float* src = inps + pix0 * 256;
#pragma unroll
  for (int it = 0; it < 8; ++it) {
    int idx = it * 512 + t;           // 4096 float4 groups
    int row = idx >> 6, c4 = (idx & 63) << 2;
    float4 v = *(const float4*)(src + row * 256 + c4);
    *(uint2*)&ldsA[row][c4] = make_uint2(pk2(v.x, v.y), pk2(v.z, v.w));
  }
  __syncthreads();

  int wave = t >> 6, lane = t & 63;
  int mw = wave >> 2, nw = wave & 3;
  int m0 = mw * 32, n0 = nw * 64;
  int lm = lane & 15, q = lane >> 4;
  bool gatew = (nw == 0);

  f32x4 acc[2][4], accg[2];
#pragma unroll
  for (int mf = 0; mf < 2; ++mf) {
    accg[mf] = (f32x4){0.f, 0.f, 0.f, 0.f};
#pragma unroll
    for (int nf = 0; nf < 4; ++nf) acc[mf][nf] = (f32x4){0.f, 0.f, 0.f, 0.f};
  }
  const bf16* brow = wvT + (n0 + lm) * 256;
  const bf16* grow = wgkT + lm * 256;
  const unsigned short* arow0 = &ldsA[m0 + lm][0];
  const unsigned short* arow1 = &ldsA[m0 + 16 + lm][0];

#pragma unroll
  for (int ks = 0; ks < 8; ++ks) {
    int kof = ks * 32 + q * 8;
    bf16x8 a0 = *(const bf16x8*)(arow0 + kof);
    bf16x8 a1 = *(const bf16x8*)(arow1 + kof);
    bf16x8 b0 = *(const bf16x8*)(brow + kof);
    bf16x8 b1 = *(const bf16x8*)(brow + 4096 + kof);
    bf16x8 b2 = *(const bf16x8*)(brow + 8192 + kof);
    bf16x8 b3 = *(const bf16x8*)(brow + 12288 + kof);
    acc[0][0] = __builtin_amdgcn_mfma_f32_16x16x32_bf16(a0, b0, acc[0][0], 0, 0, 0);
    acc[1][0] = __builtin_amdgcn_mfma_f32_16x16x32_bf16(a1, b0, acc[1][0], 0, 0, 0);
    acc[0][1] = __builtin_amdgcn_mfma_f32_16x16x32_bf16(a0, b1, acc[0][1], 0, 0, 0);
    acc[1][1] = __builtin_amdgcn_mfma_f32_16x16x32_bf16(a1, b1, acc[1][1], 0, 0, 0);
    acc[0][2] = __builtin_amdgcn_mfma_f32_16x16x32_bf16(a0, b2, acc[0][2], 0, 0, 0);
    acc[1][2] = __builtin_amdgcn_mfma_f32_16x16x32_bf16(a1, b2, acc[1][2], 0, 0, 0);
    acc[0][3] = __builtin_amdgcn_mfma_f32_16x16x32_bf16(a0, b3, acc[0][3], 0, 0, 0);
    acc[1][3] = __builtin_amdgcn_mfma_f32_16x16x32_bf16(a1, b3, acc[1][3], 0, 0, 0);
    if (gatew) {
      bf16x8 bg = *(const bf16x8*)(grow + kof);
      accg[0] = __builtin_amdgcn_mfma_f32_16x16x32_bf16(a0, bg, accg[0], 0, 0, 0);
      accg[1] = __builtin_amdgcn_mfma_f32_16x16x32_bf16(a1, bg, accg[1], 0, 0, 0);
    }
  }

  // vraw epilogue (bias only; scale applied in kB)
#pragma unroll
  for (int nf = 0; nf < 4; ++nf) {
    int col = n0 + nf * 16 + lm;
    float wb = wv_b[col];
#pragma unroll
    for (int mf = 0; mf < 2; ++mf) {
#pragma unroll
      for (int r = 0; r < 4; ++r) {
        int rl = m0 + mf * 16 + q * 4 + r;
        vraw[(pix0 + rl) * 256 + col] = __float2bfloat16(acc[mf][nf][r] + wb);
      }
    }
  }

  // gate epilogue
  if (gatew) {
    float part = 0.f;
    if (lm < 8) {
#pragma unroll
      for (int mf = 0; mf < 2; ++mf) {
#pragma unroll
        for (int r = 0; r < 4; ++r) {
          int rl = m0 + mf * 16 + q * 4 + r;
          float gg = fmaxf(qvb_s[lm] + accg[mf][r], 0.f);
          gbuf[(pix0 + rl) * 8 + lm] = gg;
          part += gg;
        }
      }
    }
    part += __shfl_xor(part, 16, 64);
    part += __shfl_xor(part, 32, 64);
    if (lane < 16 && lm < 8) atomicAdd(&sden[lm], part);
  }
  __syncthreads();
  if (t < 8) atomicAdd(&denom[(int)(pix0 >> 12) * 8 + t], sden[t]);
}

// ---------------------------------------------------------------------------
// kB (fused scale + patch gather + final GEMM). Block = (b,x) row, 256 thr.
// Phase 0: stage scf[i][c][a] = 4096/(denom+eps)*g for the 4 source rows.
// Phase 1: op[y][ch] = sum_taps (s0*scf) * vraw   (uint = 2ch per lane)
// Phase 2: out = op @ wf + wf_b via MFMA (wfT in L2).
// ---------------------------------------------------------------------------
__global__ __launch_bounds__(256) void kB(
    const bf16* __restrict__ vraw, const float* __restrict__ s0,
    const float* __restrict__ gbuf, const float* __restrict__ denom,
    const bf16* __restrict__ wfT, const float* __restrict__ wf_b,
    float* __restrict__ out) {
  __shared__ float scfsh[4][64][8];                      // 8 KB
  __shared__ __align__(16) unsigned short opsh[32][264]; // bf16 bits
  int t = threadIdx.x;
  int bx = blockIdx.x, b = bx >> 5, x = bx & 31;

  { // phase 0
    int i = t >> 6, c = t & 63;
    int r = 2 * x + i - 1;
    if (r >= 0 && r < 64) {
      long p = (long)b * 4096 + r * 64 + c;
#pragma unroll
      for (int a = 0; a < 8; ++a)
        scfsh[i][c][a] = 4096.0f / (denom[b * 8 + a] + 1e-6f) * gbuf[p * 8 + a];
    } else {
#pragma unroll
      for (int a = 0; a < 8; ++a) scfsh[i][c][a] = 0.f;
    }
  }
  __syncthreads();

  // phase 1
  int c2 = t & 127, yg = t >> 7;
  int h = c2 >> 4;
  float s0r[16];
#pragma unroll
  for (int n = 0; n < 16; ++n) s0r[n] = s0[h * 16 + n];
  const bf16* vsb = vraw + (long)b * (4096 * 256);
  for (int yi = 0; yi < 16; ++yi) {
    int y = yi * 2 + yg;
    float p0 = 0.f, p1 = 0.f;
#pragma unroll
    for (int i = 0; i < 4; ++i) {
      int r = 2 * x + i - 1;
      if (r < 0 || r >= 64) continue;               // block-uniform
      const bf16* rowp = vsb + (long)r * 64 * 256 + 2 * c2;
#pragma unroll
      for (int j = 0; j < 4; ++j) {
        int c = 2 * y + j - 1;
        if (c < 0 || c >= 64) continue;             // wave-uniform
        float coef = s0r[i * 4 + j] * scfsh[i][c][h];
        unsigned u = *(const unsigned*)(rowp + (long)c * 256);
        p0 += coef * bf2f((unsigned short)(u & 0xffff));
        p1 += coef * bf2f((unsigned short)(u >> 16));
      }
    }
    *(unsigned*)&opsh[y][2 * c2] = pk2(p0, p1);
  }
  __syncthreads();

  // phase 2: MFMA  out[32x256] = op @ wf + b
  int wave = t >> 6, lane = t & 63;
  int n0 = wave * 64;
  int lm = lane & 15, q = lane >> 4;
  f32x4 acc[2][4];
#pragma unroll
  for (int mf = 0; mf < 2; ++mf)
#pragma unroll
    for (int nf = 0; nf < 4; ++nf) acc[mf][nf] = (f32x4){0.f, 0.f, 0.f, 0.f};
  const bf16* brow = wfT + (n0 + lm) * 256;
#pragma unroll
  for (int ks = 0; ks < 8; ++ks) {
    int kof = ks * 32 + q * 8;
    bf16x8 a0 = *(const bf16x8*)(&opsh[lm][kof]);
    bf16x8 a1 = *(const bf16x8*)(&opsh[16 + lm][kof]);
#pragma unroll
    for (int nf = 0; nf < 4; ++nf) {
      bf16x8 bb = *(const bf16x8*)(brow + nf * 4096 + kof);
      acc[0][nf] = __builtin_amdgcn_mfma_f32_16x16x32_bf16(a0, bb, acc[0][nf], 0, 0, 0);
      acc[1][nf] = __builtin_amdgcn_mfma_f32_16x16x32_bf16(a1, bb, acc[1][nf], 0, 0, 0);
    }
  }
  long out0 = (long)bx * 32 * 256;
#pragma unroll
  for (int nf = 0; nf < 4; ++nf) {
    int col = n0 + nf * 16 + lm;
    float wb = wf_b[col];
#pragma unroll
    for (int mf = 0; mf < 2; ++mf) {
#pragma unroll
      for (int r = 0; r < 4; ++r) {
        int row = mf * 16 + q * 4 + r;
        out[out0 + row * 256 + col] = acc[mf][nf][r] + wb;
      }
    }
  }
}

// ---------------------------------------------------------------------------
// Workspace (float offsets): s0 0 | qv 128 | denom 256 | gbuf 1024 (+1M)
// wvT @1049600 (+32768) | wfT @1082368 (+32768) | wgkT @1115136 (+2048)
// vraw(bf16) @1117184 (+16.7M f-equiv). Total ~71.6 MB.
// ---------------------------------------------------------------------------
extern "C" void kernel_launch(void* const* d_in, const int* in_sizes, int n_in,
                              void* d_out, int out_size, void* d_ws, size_t ws_size,
                              hipStream_t stream) {
  const float* inps  = (const float*)d_in[0];
  const float* emb   = (const float*)d_in[1];
  const float* wkq_w = (const float*)d_in[2];
  const float* wkq_b = (const float*)d_in[3];
  const float* wv_w  = (const float*)d_in[4];
  const float* wv_b  = (const float*)d_in[5];
  const float* wgq_w = (const float*)d_in[6];
  const float* wgq_b = (const float*)d_in[7];
  const float* wgk_w = (const float*)d_in[8];
  const float* wgk_b = (const float*)d_in[9];
  const float* wf_w  = (const float*)d_in[10];
  const float* wf_b  = (const float*)d_in[11];

  float* wsf   = (float*)d_ws;
  float* s0f   = wsf;
  float* qvf   = wsf + 128;
  float* denom = wsf + 256;
  float* gbuf  = wsf + 1024;
  bf16*  wvT   = (bf16*)(wsf + 1049600);
  bf16*  wfT   = (bf16*)(wsf + 1082368);
  bf16*  wgkT  = (bf16*)(wsf + 1115136);
  bf16*  vraw  = (bf16*)(wsf + 1117184);
  float* outp  = (float*)d_out;

  hipMemsetAsync((void*)denom, 0, 1024, stream);
  k1_setup<<<1, 256, 0, stream>>>(emb, wkq_w, wkq_b, wgq_w, wgq_b, s0f, qvf);
  prep<<<33, 256, 0, stream>>>(wv_w, wf_w, wgk_w, wvT, wfT, wgkT);
  kA<<<PIX_ / 64, 512, 0, stream>>>(inps, wvT, wgkT, wv_b, wgk_b, qvf,
                                    vraw, gbuf, denom);
  kB<<<OUTPIX_ / 32, 256, 0, stream>>>(vraw, s0f, gbuf, denom, wfT, wf_b, outp);
}